// Round 4
// baseline (473.184 us; speedup 1.0000x reference)
//
#include <hip/hip_runtime.h>
#include <stdint.h>

// ---------------------------------------------------------------------------
// GCN 3-layer forward:  out = A_hat @ relu(A_hat @ relu(A_hat @ x W0 + b0) W1 + b1) W2 + b2
// A_hat = D^-1/2 (A + I) D^-1/2. With pre-scaled rows h'[r] = dinv[r]*h[r]:
//   out[c] = dinv[c] * ( sum_{edges r->c} h'[r] + h'[c] ) + b
//
// R2: agg FETCH == 8 XCD x sizeof(H) (random graph) -> H stored bf16.
// R3: one-shot scatter was 64B-partial-line bound -> bucketed 2-pass sort.
// R4: feature-sliced gather: slice slab per XCD L2. FETCH 195->60 MB.
// R8: pre-scale H by dinv at GEMM output -> agg per-edge work = gather+add.
// R9: 32-feat slices, uint2 gathers (full 64B line), halved chain count.
// R10: MFMA gemm, 3-term bf16 split (Ah*Bh+Al*Bh+Ah*Bl). gemm 70->~40us.
//   BUT R9's 6.4MB slab > 4MB L2 -> agg FETCH 200MB (120MB thrash), agg
//   BW-bound at 3.7TB/s.
// R11: explicit source-half split. epk grouped (dest, src-half) via mid[].
//   agg128 = 8 combos (4 slice x 2 half), one per XCD, 3.2MB half-slab ->
//   L2-resident, zero thrash. Halves write fp32 partials (h0: +self_lo
//   +bias -> abuf; h1: +self_hi -> pbuf); next gemm sums partials + relu
//   in its X-stage (exact: everything pre-relu is linear). agg64 untouched
//   (full-range iteration; reordering invisible).
// ---------------------------------------------------------------------------

static inline size_t ws_align(size_t x) { return (x + 255) & ~(size_t)255; }

typedef float __f2 __attribute__((ext_vector_type(2)));
typedef float __f4 __attribute__((ext_vector_type(4)));
typedef __attribute__((ext_vector_type(8))) short short8v;
typedef __attribute__((ext_vector_type(4))) float f32x4;

__device__ __forceinline__ int eidx(const void* p, size_t i, int is64) {
  return is64 ? (int)((const long long*)p)[i] : ((const int*)p)[i];
}

__device__ __forceinline__ uint16_t f2bf(float f) {  // RNE float->bf16
  uint32_t u = __float_as_uint(f);
  u += 0x7fffu + ((u >> 16) & 1u);
  return (uint16_t)(u >> 16);
}
__device__ __forceinline__ float bf_lo(uint32_t h) { return __uint_as_float(h << 16); }
__device__ __forceinline__ float bf_hi(uint32_t h) { return __uint_as_float(h & 0xffff0000u); }

// Detect int64 vs int32 edge_index (little-endian: int64 high words are 0).
__global__ void detect_k(const int* ei, int* flag) {
  if (threadIdx.x == 0 && blockIdx.x == 0) {
    int allz = 1;
    for (int i = 1; i < 128; i += 2)
      if (ei[i] != 0) { allz = 0; break; }
    *flag = allz;
  }
}

// --- passA: bucket histogram via per-block LDS counters --------------------
__global__ __launch_bounds__(256) void passA_k(const void* ei, const int* __restrict__ flag,
                                               int* __restrict__ bucket_cnt, int E, int NB) {
  __shared__ int cnt[256];
  int t = threadIdx.x;
  cnt[t] = 0;
  __syncthreads();
  int is64 = *flag;
  for (int e = blockIdx.x * 256 + t; e < E; e += gridDim.x * 256) {
    int c = eidx(ei, (size_t)E + e, is64);
    atomicAdd(&cnt[c >> 9], 1);
  }
  __syncthreads();
  if (t < NB && cnt[t]) atomicAdd(&bucket_cnt[t], cnt[t]);
}

// --- bscan: exclusive scan of bucket_cnt -> bucket_offs; init gcursor ------
__global__ __launch_bounds__(256) void bscan_k(const int* __restrict__ bucket_cnt,
                                               int* __restrict__ bucket_offs,
                                               int* __restrict__ gcursor, int NB) {
  __shared__ int sh[256];
  int t = threadIdx.x;
  int v = (t < NB) ? bucket_cnt[t] : 0;
  sh[t] = v;
  __syncthreads();
  for (int off = 1; off < 256; off <<= 1) {
    int x = (t >= off) ? sh[t - off] : 0;
    __syncthreads();
    sh[t] += x;
    __syncthreads();
  }
  if (t < NB) {
    int excl = sh[t] - v;
    bucket_offs[t] = excl;
    gcursor[t] = excl;
  }
  if (t == NB - 1) bucket_offs[NB] = sh[t];
}

// --- passB: partition edges into bucket-contiguous epk_binned --------------
__global__ __launch_bounds__(256) void passB_k(const void* ei, const int* __restrict__ flag,
                                               int* __restrict__ gcursor,
                                               int2* __restrict__ epk_binned, int E, int NB) {
  __shared__ int2 sorted[4096];                       // 32 KB
  __shared__ int cnt[256], bbase[256], gb[256], cur[256];
  const int t = threadIdx.x;
  const int base = blockIdx.x * 4096;
  const int CH = min(4096, E - base);
  const int is64 = *flag;

  cnt[t] = 0;
  __syncthreads();
  for (int i = t; i < CH; i += 256) {
    int c = eidx(ei, (size_t)E + base + i, is64);
    atomicAdd(&cnt[c >> 9], 1);
  }
  __syncthreads();
  {
    int v = cnt[t];
    __shared__ int sh[256];
    sh[t] = v;
    __syncthreads();
    for (int off = 1; off < 256; off <<= 1) {
      int x = (t >= off) ? sh[t - off] : 0;
      __syncthreads();
      sh[t] += x;
      __syncthreads();
    }
    bbase[t] = sh[t] - v;
    gb[t] = (t < NB && v) ? atomicAdd(&gcursor[t], v) : 0;
    cur[t] = 0;
  }
  __syncthreads();
  for (int i = t; i < CH; i += 256) {
    int r = eidx(ei, (size_t)base + i, is64);
    int c = eidx(ei, (size_t)E + base + i, is64);
    int b = c >> 9;
    int rank = atomicAdd(&cur[b], 1);
    sorted[bbase[b] + rank] = make_int2(r, c);
  }
  __syncthreads();
  for (int i = t; i < CH; i += 256) {
    int2 v = sorted[i];
    int b = v.y >> 9;
    epk_binned[gb[b] + (i - bbase[b])] = v;
  }
}

// --- passC0: per-(dest,half) counts -> deg[], offs[], mid[] ----------------
__global__ __launch_bounds__(256) void passC0_k(const int2* __restrict__ epk_binned,
                                                const int* __restrict__ bucket_offs,
                                                int* __restrict__ deg, int* __restrict__ offs,
                                                int* __restrict__ mid,
                                                int n, int NB, int NH) {
  __shared__ int dcnt[1024];
  __shared__ int s[256];
  const int t = threadIdx.x;
  const int b = blockIdx.x;
  dcnt[t] = 0; dcnt[t + 256] = 0; dcnt[t + 512] = 0; dcnt[t + 768] = 0;
  __syncthreads();
  const int lo = bucket_offs[b], hi = bucket_offs[b + 1];
  for (int i = lo + t; i < hi; i += 256) {
    int2 v = epk_binned[i];
    int hf = (v.x >= NH) ? 1 : 0;
    atomicAdd(&dcnt[((v.y & 511) << 1) | hf], 1);
  }
  __syncthreads();
  int c00 = dcnt[4 * t], c01 = dcnt[4 * t + 1];
  int c10 = dcnt[4 * t + 2], c11 = dcnt[4 * t + 3];
  int d0 = c00 + c01, d1 = c10 + c11;
  int pv = d0 + d1;
  s[t] = pv;
  __syncthreads();
  for (int off = 1; off < 256; off <<= 1) {
    int x = (t >= off) ? s[t - off] : 0;
    __syncthreads();
    s[t] += x;
    __syncthreads();
  }
  int pex = s[t] - pv;
  const int node0 = b << 9;
  int g0 = node0 + 2 * t, g1 = node0 + 2 * t + 1;
  if (g0 < n) { deg[g0] = d0; offs[g0] = lo + pex; mid[g0] = lo + pex + c00; }
  if (g1 < n) { deg[g1] = d1; offs[g1] = lo + pex + d0; mid[g1] = lo + pex + d0 + c10; }
  if (b == NB - 1 && t == 0) offs[n] = hi;
}

__global__ void dinv_k(const int* __restrict__ deg, float* __restrict__ dinv, int n) {
  int i = blockIdx.x * blockDim.x + threadIdx.x;
  if (i < n) dinv[i] = rsqrtf((float)deg[i] + 1.0f);  // +1 = self loop
}

// --- passC: final placement by (dest, half); entry = plain src -------------
__global__ __launch_bounds__(256) void passC_k(const int2* __restrict__ epk_binned,
                                               const int* __restrict__ bucket_offs,
                                               const int* __restrict__ offs,
                                               const int* __restrict__ mid,
                                               uint32_t* __restrict__ epk, int NH) {
  __shared__ int cur[1024];
  const int t = threadIdx.x;
  const int b = blockIdx.x;
  cur[t] = 0; cur[t + 256] = 0; cur[t + 512] = 0; cur[t + 768] = 0;
  __syncthreads();
  const int lo = bucket_offs[b], hi = bucket_offs[b + 1];
  for (int i = lo + t; i < hi; i += 256) {
    int2 v = epk_binned[i];
    int hf = (v.x >= NH) ? 1 : 0;
    int base = hf ? mid[v.y] : offs[v.y];
    int pos = base + atomicAdd(&cur[((v.y & 511) << 1) | hf], 1);
    epk[pos] = (uint32_t)v.x;
  }
}

// --- wprep: split W fp32 -> bf16 hi/lo MFMA fragments in global ------------
template <int COLS>
__global__ void wprep_k(const float* __restrict__ W, uint16_t* __restrict__ Wf) {
  constexpr int CT = COLS / 16;
  const int f = blockIdx.x;  // [0, 4*CT)
  const int kc = f / CT, ct = f % CT;
  const int l = threadIdx.x;  // 0..63
#pragma unroll
  for (int j = 0; j < 8; ++j) {
    int k = kc * 32 + (l >> 4) * 8 + j;
    int col = ct * 16 + (l & 15);
    float wv = W[(size_t)k * COLS + col];
    uint16_t hi = f2bf(wv);
    float res = wv - __uint_as_float((uint32_t)hi << 16);
    Wf[(size_t)f * 1024 + l * 8 + j] = hi;
    Wf[(size_t)f * 1024 + 512 + l * 8 + j] = f2bf(res);
  }
}

// --- MFMA GEMM: Hs (32-feat-sliced bf16) = dinv[row] * (relu?(X[+X2]) @ W) -
// SLICED_IN: X = abuf partial0, X2 = pbuf partial1; x = relu(x0+x1).
template <int COLS, bool SLICED_IN>
__global__ __launch_bounds__(256) void gemm_k(const float* __restrict__ X,
                                              const float* __restrict__ X2,
                                              const uint16_t* __restrict__ Wf,
                                              const float* __restrict__ dinv,
                                              uint16_t* __restrict__ H, int N) {
  constexpr int CT = COLS / 16;
  __shared__ uint32_t Xp[128 * 32];  // 16 KB

  const int tid = threadIdx.x;
  const int l = tid & 63, w = tid >> 6;
  const int rowbase = blockIdx.x * 128;
  const float4* X4 = (const float4*)X;
  const float4* P4 = (const float4*)X2;

  f32x4 acc[2][CT];
#pragma unroll
  for (int rt = 0; rt < 2; ++rt)
#pragma unroll
    for (int ct = 0; ct < CT; ++ct) acc[rt][ct] = (f32x4)0.f;

  for (int kc = 0; kc < 4; ++kc) {
    __syncthreads();
    // stage X chunk: 128 rows x 32 k, packed bf16 hi/lo, swizzled
#pragma unroll
    for (int t = 0; t < 4; ++t) {
      int i = tid + t * 256;  // 0..1023
      int r = i >> 3, q = i & 7;
      int gr = rowbase + r;
      if (gr >= N) gr = N - 1;
      float4 xv;
      if (SLICED_IN) {
        float4 v0 = X4[((size_t)kc * N + gr) * 8 + q];
        float4 v1 = P4[((size_t)kc * N + gr) * 8 + q];
        xv.x = fmaxf(v0.x + v1.x, 0.f);
        xv.y = fmaxf(v0.y + v1.y, 0.f);
        xv.z = fmaxf(v0.z + v1.z, 0.f);
        xv.w = fmaxf(v0.w + v1.w, 0.f);
      } else {
        xv = X4[(size_t)gr * 32 + kc * 8 + q];
      }
      float xs[4] = {xv.x, xv.y, xv.z, xv.w};
      uint32_t p[4];
#pragma unroll
      for (int e = 0; e < 4; ++e) {
        uint16_t hi = f2bf(xs[e]);
        float res = xs[e] - __uint_as_float((uint32_t)hi << 16);
        p[e] = ((uint32_t)hi << 16) | (uint32_t)f2bf(res);
      }
      int blk = q ^ (r & 7);
      *(uint4*)&Xp[r * 32 + blk * 4] = make_uint4(p[0], p[1], p[2], p[3]);
    }
    __syncthreads();

    // A fragments (2 row-tiles), unpack hi/lo via v_perm
    short8v ah[2], al[2];
#pragma unroll
    for (int rt = 0; rt < 2; ++rt) {
      int r = w * 32 + rt * 16 + (l & 15);
      int c = (r & 7) << 2;
      int b0 = ((l >> 4) * 8) ^ c;
      int b1 = ((l >> 4) * 8 + 4) ^ c;
      uint32_t ua[8];
      *(uint4*)&ua[0] = *(const uint4*)&Xp[r * 32 + b0];
      *(uint4*)&ua[4] = *(const uint4*)&Xp[r * 32 + b1];
      union { uint32_t d[4]; short8v v; } ch, cl;
#pragma unroll
      for (int p2 = 0; p2 < 4; ++p2) {
        ch.d[p2] = __builtin_amdgcn_perm(ua[2 * p2 + 1], ua[2 * p2], 0x07060302u);
        cl.d[p2] = __builtin_amdgcn_perm(ua[2 * p2 + 1], ua[2 * p2], 0x05040100u);
      }
      ah[rt] = ch.v;
      al[rt] = cl.v;
    }

    // B fragments from global (L2), 3-term mfma
#pragma unroll
    for (int ct = 0; ct < CT; ++ct) {
      size_t fo = (size_t)(kc * CT + ct) * 1024;
      short8v bh = *(const short8v*)(Wf + fo + l * 8);
      short8v bl = *(const short8v*)(Wf + fo + 512 + l * 8);
#pragma unroll
      for (int rt = 0; rt < 2; ++rt) {
        acc[rt][ct] = __builtin_amdgcn_mfma_f32_16x16x32_bf16(ah[rt], bh, acc[rt][ct], 0, 0, 0);
        acc[rt][ct] = __builtin_amdgcn_mfma_f32_16x16x32_bf16(al[rt], bh, acc[rt][ct], 0, 0, 0);
        acc[rt][ct] = __builtin_amdgcn_mfma_f32_16x16x32_bf16(ah[rt], bl, acc[rt][ct], 0, 0, 0);
      }
    }
  }

  // Epilogue: D col=lane&15, row=(lane>>4)*4+reg. Pair even/odd cols via
  // shfl_xor -> uint32 words, sliced-bf16 H layout (same as agg expects).
  uint32_t* HW = (uint32_t*)H;
  const int lq = l >> 4, lc = l & 15;
#pragma unroll
  for (int rt = 0; rt < 2; ++rt) {
#pragma unroll
    for (int q = 0; q < 4; ++q) {
      int row = rowbase + w * 32 + rt * 16 + lq * 4 + q;
      bool ok = row < N;
      float dv = ok ? dinv[row] : 0.f;
#pragma unroll
      for (int ct = 0; ct < CT; ++ct) {
        float v = acc[rt][ct][q] * dv;
        int b = (int)f2bf(v);
        int other = __shfl_xor(b, 1);
        if (ok && !(l & 1)) {
          uint32_t word = (uint32_t)b | ((uint32_t)other << 16);
          HW[((size_t)(ct >> 1) * N + row) * 16 + (ct & 1) * 8 + (lc >> 1)] = word;
        }
      }
    }
  }
}

// --- Sliced half-split aggregate, 128 feats --------------------------------
// combo = blockIdx&7 -> XCD; slice s = combo&3, src-half h = combo>>2.
// Each XCD gathers only from its 3.2MB half-slab (L2-resident).
// Partial h0 -> P0 (+self if c<NH, +bias); partial h1 -> P1 (+self if c>=NH).
// relu deferred to consumer gemm.
__global__ __launch_bounds__(256, 8) void agg128s_k(const uint32_t* __restrict__ HW,
                                                    const int* __restrict__ offs,
                                                    const int* __restrict__ mid,
                                                    const uint32_t* __restrict__ epk,
                                                    const float* __restrict__ bias,
                                                    float* __restrict__ P0,
                                                    float* __restrict__ P1,
                                                    int NH, int N) {
  const int combo = blockIdx.x & 7;
  const int s = combo & 3;
  const int h = combo >> 2;
  const int g = blockIdx.x >> 3;
  const int lane = threadIdx.x & 63;
  const int wid = threadIdx.x >> 6;
  const int d = lane >> 3, w = lane & 7;
  const int c = g * 32 + wid * 8 + d;
  if (c >= N) return;
  const uint32_t* Hs = HW + (size_t)s * N * 16;
  int eb = offs[c], ee = offs[c + 1], em = mid[c];
  int e0 = h ? em : eb;
  int e1 = h ? ee : em;
  float a0 = 0.f, a1 = 0.f, a2 = 0.f, a3 = 0.f;
  int e = e0;
  for (; e + 8 <= e1; e += 8) {
    uint32_t p0 = epk[e],     p1 = epk[e + 1], p2 = epk[e + 2], p3 = epk[e + 3];
    uint32_t p4 = epk[e + 4], p5 = epk[e + 5], p6 = epk[e + 6], p7 = epk[e + 7];
    uint2 h0 = *(const uint2*)&Hs[(size_t)p0 * 16 + 2 * w];
    uint2 h1 = *(const uint2*)&Hs[(size_t)p1 * 16 + 2 * w];
    uint2 h2 = *(const uint2*)&Hs[(size_t)p2 * 16 + 2 * w];
    uint2 h3 = *(const uint2*)&Hs[(size_t)p3 * 16 + 2 * w];
    uint2 h4 = *(const uint2*)&Hs[(size_t)p4 * 16 + 2 * w];
    uint2 h5 = *(const uint2*)&Hs[(size_t)p5 * 16 + 2 * w];
    uint2 h6 = *(const uint2*)&Hs[(size_t)p6 * 16 + 2 * w];
    uint2 h7 = *(const uint2*)&Hs[(size_t)p7 * 16 + 2 * w];
    a0 += bf_lo(h0.x); a1 += bf_hi(h0.x); a2 += bf_lo(h0.y); a3 += bf_hi(h0.y);
    a0 += bf_lo(h1.x); a1 += bf_hi(h1.x); a2 += bf_lo(h1.y); a3 += bf_hi(h1.y);
    a0 += bf_lo(h2.x); a1 += bf_hi(h2.x); a2 += bf_lo(h2.y); a3 += bf_hi(h2.y);
    a0 += bf_lo(h3.x); a1 += bf_hi(h3.x); a2 += bf_lo(h3.y); a3 += bf_hi(h3.y);
    a0 += bf_lo(h4.x); a1 += bf_hi(h4.x); a2 += bf_lo(h4.y); a3 += bf_hi(h4.y);
    a0 += bf_lo(h5.x); a1 += bf_hi(h5.x); a2 += bf_lo(h5.y); a3 += bf_hi(h5.y);
    a0 += bf_lo(h6.x); a1 += bf_hi(h6.x); a2 += bf_lo(h6.y); a3 += bf_hi(h6.y);
    a0 += bf_lo(h7.x); a1 += bf_hi(h7.x); a2 += bf_lo(h7.y); a3 += bf_hi(h7.y);
  }
  for (; e + 4 <= e1; e += 4) {
    uint32_t p0 = epk[e], p1 = epk[e + 1], p2 = epk[e + 2], p3 = epk[e + 3];
    uint2 h0 = *(const uint2*)&Hs[(size_t)p0 * 16 + 2 * w];
    uint2 h1 = *(const uint2*)&Hs[(size_t)p1 * 16 + 2 * w];
    uint2 h2 = *(const uint2*)&Hs[(size_t)p2 * 16 + 2 * w];
    uint2 h3 = *(const uint2*)&Hs[(size_t)p3 * 16 + 2 * w];
    a0 += bf_lo(h0.x); a1 += bf_hi(h0.x); a2 += bf_lo(h0.y); a3 += bf_hi(h0.y);
    a0 += bf_lo(h1.x); a1 += bf_hi(h1.x); a2 += bf_lo(h1.y); a3 += bf_hi(h1.y);
    a0 += bf_lo(h2.x); a1 += bf_hi(h2.x); a2 += bf_lo(h2.y); a3 += bf_hi(h2.y);
    a0 += bf_lo(h3.x); a1 += bf_hi(h3.x); a2 += bf_lo(h3.y); a3 += bf_hi(h3.y);
  }
  for (; e < e1; ++e) {
    uint2 h2 = *(const uint2*)&Hs[(size_t)epk[e] * 16 + 2 * w];
    a0 += bf_lo(h2.x); a1 += bf_hi(h2.x); a2 += bf_lo(h2.y); a3 += bf_hi(h2.y);
  }
  float dc = rsqrtf((float)(ee - eb) + 1.f);
  bool match = ((c >= NH) ? 1 : 0) == h;
  if (match) {
    uint2 hc = *(const uint2*)&Hs[(size_t)c * 16 + 2 * w];
    a0 += bf_lo(hc.x); a1 += bf_hi(hc.x);
    a2 += bf_lo(hc.y); a3 += bf_hi(hc.y);
  }
  float b0v = 0.f, b1v = 0.f, b2v = 0.f, b3v = 0.f;
  if (h == 0) {
    b0v = bias[s * 32 + 4 * w + 0];
    b1v = bias[s * 32 + 4 * w + 1];
    b2v = bias[s * 32 + 4 * w + 2];
    b3v = bias[s * 32 + 4 * w + 3];
  }
  __f4 res;
  res.x = fmaf(dc, a0, b0v);
  res.y = fmaf(dc, a1, b1v);
  res.z = fmaf(dc, a2, b2v);
  res.w = fmaf(dc, a3, b3v);
  float* O = h ? P1 : P0;
  __builtin_nontemporal_store(res, (__f4*)(O + ((size_t)s * N + c) * 32 + 4 * w));
}

// --- Sliced aggregate, 64 feats: 2 slices x 32 on XCD quads; dense out -----
__global__ __launch_bounds__(256, 8) void agg64s_k(const uint32_t* __restrict__ HW,
                                                   const int* __restrict__ offs,
                                                   const uint32_t* __restrict__ epk,
                                                   const float* __restrict__ bias,
                                                   float* __restrict__ out, int N) {
  const int r = blockIdx.x & 7;
  const int s = r >> 2;          // slice 0..1 (32 feats each)
  const int quar = r & 3;
  const int ng = (N + 31) >> 5;
  const int nq = (ng + 3) >> 2;
  const int g = quar * nq + (blockIdx.x >> 3);
  if (g >= ng) return;
  const int lane = threadIdx.x & 63;
  const int wid = threadIdx.x >> 6;
  const int d = lane >> 3, w = lane & 7;
  const int c = g * 32 + wid * 8 + d;
  if (c >= N) return;
  const uint32_t* Hs = HW + (size_t)s * N * 16;
  int e0 = offs[c], e1 = offs[c + 1];
  float a0 = 0.f, a1 = 0.f, a2 = 0.f, a3 = 0.f;
  int e = e0;
  for (; e + 8 <= e1; e += 8) {
    uint32_t p0 = epk[e],     p1 = epk[e + 1], p2 = epk[e + 2], p3 = epk[e + 3];
    uint32_t p4 = epk[e + 4], p5 = epk[e + 5], p6 = epk[e + 6], p7 = epk[e + 7];
    uint2 h0 = *(const uint2*)&Hs[(size_t)p0 * 16 + 2 * w];
    uint2 h1 = *(const uint2*)&Hs[(size_t)p1 * 16 + 2 * w];
    uint2 h2 = *(const uint2*)&Hs[(size_t)p2 * 16 + 2 * w];
    uint2 h3 = *(const uint2*)&Hs[(size_t)p3 * 16 + 2 * w];
    uint2 h4 = *(const uint2*)&Hs[(size_t)p4 * 16 + 2 * w];
    uint2 h5 = *(const uint2*)&Hs[(size_t)p5 * 16 + 2 * w];
    uint2 h6 = *(const uint2*)&Hs[(size_t)p6 * 16 + 2 * w];
    uint2 h7 = *(const uint2*)&Hs[(size_t)p7 * 16 + 2 * w];
    a0 += bf_lo(h0.x); a1 += bf_hi(h0.x); a2 += bf_lo(h0.y); a3 += bf_hi(h0.y);
    a0 += bf_lo(h1.x); a1 += bf_hi(h1.x); a2 += bf_lo(h1.y); a3 += bf_hi(h1.y);
    a0 += bf_lo(h2.x); a1 += bf_hi(h2.x); a2 += bf_lo(h2.y); a3 += bf_hi(h2.y);
    a0 += bf_lo(h3.x); a1 += bf_hi(h3.x); a2 += bf_lo(h3.y); a3 += bf_hi(h3.y);
    a0 += bf_lo(h4.x); a1 += bf_hi(h4.x); a2 += bf_lo(h4.y); a3 += bf_hi(h4.y);
    a0 += bf_lo(h5.x); a1 += bf_hi(h5.x); a2 += bf_lo(h5.y); a3 += bf_hi(h5.y);
    a0 += bf_lo(h6.x); a1 += bf_hi(h6.x); a2 += bf_lo(h6.y); a3 += bf_hi(h6.y);
    a0 += bf_lo(h7.x); a1 += bf_hi(h7.x); a2 += bf_lo(h7.y); a3 += bf_hi(h7.y);
  }
  for (; e + 4 <= e1; e += 4) {
    uint32_t p0 = epk[e], p1 = epk[e + 1], p2 = epk[e + 2], p3 = epk[e + 3];
    uint2 h0 = *(const uint2*)&Hs[(size_t)p0 * 16 + 2 * w];
    uint2 h1 = *(const uint2*)&Hs[(size_t)p1 * 16 + 2 * w];
    uint2 h2 = *(const uint2*)&Hs[(size_t)p2 * 16 + 2 * w];
    uint2 h3 = *(const uint2*)&Hs[(size_t)p3 * 16 + 2 * w];
    a0 += bf_lo(h0.x); a1 += bf_hi(h0.x); a2 += bf_lo(h0.y); a3 += bf_hi(h0.y);
    a0 += bf_lo(h1.x); a1 += bf_hi(h1.x); a2 += bf_lo(h1.y); a3 += bf_hi(h1.y);
    a0 += bf_lo(h2.x); a1 += bf_hi(h2.x); a2 += bf_lo(h2.y); a3 += bf_hi(h2.y);
    a0 += bf_lo(h3.x); a1 += bf_hi(h3.x); a2 += bf_lo(h3.y); a3 += bf_hi(h3.y);
  }
  for (; e < e1; ++e) {
    uint2 h = *(const uint2*)&Hs[(size_t)epk[e] * 16 + 2 * w];
    a0 += bf_lo(h.x); a1 += bf_hi(h.x); a2 += bf_lo(h.y); a3 += bf_hi(h.y);
  }
  float dc = rsqrtf((float)(e1 - e0) + 1.f);
  uint2 hc = *(const uint2*)&Hs[(size_t)c * 16 + 2 * w];
  float r0 = fmaf(dc, a0 + bf_lo(hc.x), bias[s * 32 + 4 * w + 0]);
  float r1 = fmaf(dc, a1 + bf_hi(hc.x), bias[s * 32 + 4 * w + 1]);
  float r2 = fmaf(dc, a2 + bf_lo(hc.y), bias[s * 32 + 4 * w + 2]);
  float r3 = fmaf(dc, a3 + bf_hi(hc.y), bias[s * 32 + 4 * w + 3]);
  __f4 res; res.x = r0; res.y = r1; res.z = r2; res.w = r3;
  __builtin_nontemporal_store(res, (__f4*)(out + (size_t)c * 64 + s * 32 + 4 * w));
}

extern "C" void kernel_launch(void* const* d_in, const int* in_sizes, int n_in,
                              void* d_out, int out_size, void* d_ws, size_t ws_size,
                              hipStream_t stream) {
  const float* x  = (const float*)d_in[0];
  const void*  ei = d_in[1];
  const float* W0 = (const float*)d_in[2];
  const float* b0 = (const float*)d_in[3];
  const float* W1 = (const float*)d_in[4];
  const float* b1 = (const float*)d_in[5];
  const float* W2 = (const float*)d_in[6];
  const float* b2 = (const float*)d_in[7];
  float* out = (float*)d_out;

  const int n = in_sizes[0] / 128;   // 100000
  const int E = in_sizes[1] / 2;     // 1600000
  const int NB = (n + 511) >> 9;     // buckets of 512 dests (NB <= 256)
  const int NH = n >> 1;             // source half boundary

  char* ws = (char*)d_ws;
  size_t off = 0;
  auto alloc = [&](size_t bytes) { char* p = ws + off; off = ws_align(off + bytes); return p; };
  int*      bucket_cnt  = (int*)alloc(256 * 4);
  int*      bucket_offs = (int*)alloc(257 * 4);
  int*      gcursor     = (int*)alloc(256 * 4);
  int*      deg         = (int*)alloc((size_t)n * 4);
  int*      offs        = (int*)alloc((size_t)(n + 1) * 4);
  int*      mid         = (int*)alloc((size_t)n * 4);
  float*    dinv        = (float*)alloc((size_t)n * 4);
  int*      flag        = (int*)alloc(4);
  uint16_t* wf0         = (uint16_t*)alloc(64 * 1024);
  uint16_t* wf1         = (uint16_t*)alloc(64 * 1024);
  uint16_t* wf2         = (uint16_t*)alloc(32 * 1024);
  int2*     epk_binned  = (int2*)alloc((size_t)E * 8);
  uint32_t* epk         = (uint32_t*)alloc((size_t)E * 4);
  uint16_t* hbuf        = (uint16_t*)alloc((size_t)n * 128 * 2);  // sliced bf16 H'
  float*    abuf        = (float*)alloc((size_t)n * 128 * 4);     // partial h0 (fp32)
  float*    pbuf        = (float*)alloc((size_t)n * 128 * 4);     // partial h1 (fp32)
  (void)ws_size;

  hipMemsetAsync(bucket_cnt, 0, 256 * 4, stream);

  // W split/fragment prep (independent of graph passes)
  wprep_k<128><<<32, 64, 0, stream>>>(W0, wf0);
  wprep_k<128><<<32, 64, 0, stream>>>(W1, wf1);
  wprep_k<64><<<16, 64, 0, stream>>>(W2, wf2);

  detect_k<<<1, 64, 0, stream>>>((const int*)ei, flag);
  passA_k<<<512, 256, 0, stream>>>(ei, flag, bucket_cnt, E, NB);
  bscan_k<<<1, 256, 0, stream>>>(bucket_cnt, bucket_offs, gcursor, NB);
  passB_k<<<(E + 4095) / 4096, 256, 0, stream>>>(ei, flag, gcursor, epk_binned, E, NB);
  passC0_k<<<NB, 256, 0, stream>>>(epk_binned, bucket_offs, deg, offs, mid, n, NB, NH);
  dinv_k<<<(n + 255) / 256, 256, 0, stream>>>(deg, dinv, n);
  passC_k<<<NB, 256, 0, stream>>>(epk_binned, bucket_offs, offs, mid, epk, NH);

  const int gemm_blocks = (n + 127) / 128;
  const int agg128_blocks = 8 * ((n + 31) / 32);
  const int ng = (n + 31) >> 5, nq = (ng + 3) >> 2;
  const int agg64_blocks = 8 * nq;

  // Layer 0 (dense x input)
  gemm_k<128, false><<<gemm_blocks, 256, 0, stream>>>(x, nullptr, wf0, dinv, hbuf, n);
  agg128s_k<<<agg128_blocks, 256, 0, stream>>>((const uint32_t*)hbuf, offs, mid, epk, b0, abuf, pbuf, NH, n);
  // Layer 1 (partials summed + relu inside gemm X-stage)
  gemm_k<128, true><<<gemm_blocks, 256, 0, stream>>>(abuf, pbuf, wf1, dinv, hbuf, n);
  agg128s_k<<<agg128_blocks, 256, 0, stream>>>((const uint32_t*)hbuf, offs, mid, epk, b1, abuf, pbuf, NH, n);
  // Layer 2 (no relu) -> d_out dense fp32
  gemm_k<64, true><<<gemm_blocks, 256, 0, stream>>>(abuf, pbuf, wf2, dinv, hbuf, n);
  agg64s_k<<<agg64_blocks, 256, 0, stream>>>((const uint32_t*)hbuf, offs, epk, b2, out, n);
}

// Round 5
// 460.950 us; speedup vs baseline: 1.0265x; 1.0265x over previous
//
#include <hip/hip_runtime.h>
#include <stdint.h>

// ---------------------------------------------------------------------------
// GCN 3-layer forward:  out = A_hat @ relu(A_hat @ relu(A_hat @ x W0 + b0) W1 + b1) W2 + b2
// A_hat = D^-1/2 (A + I) D^-1/2. With pre-scaled rows h'[r] = dinv[r]*h[r]:
//   out[c] = dinv[c] * ( sum_{edges r->c} h'[r] + h'[c] ) + b
//
// R2: agg FETCH == 8 XCD x sizeof(H) (random graph) -> H stored bf16.
// R3: one-shot scatter was 64B-partial-line bound -> bucketed 2-pass sort.
// R4: feature-sliced gather: slice slab per XCD L2. FETCH 195->60 MB.
// R8: pre-scale H by dinv at GEMM output -> agg per-edge work = gather+add.
// R9: 32-feat slices, uint2 gathers (full 64B line), halved chain count.
// R10: MFMA gemm, 3-term bf16 split (Ah*Bh+Al*Bh+Ah*Bl). gemm 70->~40us.
//   agg slab 6.4MB > 4MB L2 -> FETCH 200MB, BW-bound 3.7TB/s, 69us. 434 tot.
// R11: src-half split for L2 residency: FETCH 200->55MB BUT dur 82us (worse):
//   doubled writes (fp32 partials x2), doubled per-dest overhead, halved
//   loops -> latency/overhead-bound at 1.9TB/s. REVERTED.
// R12: back to R10 structure + 4-lane x uint4 subgroups in agg: one wave
//   covers 16 dests (was 8), VMEM instrs/edge halved, per-dest overhead
//   per wave halved, same 64B line per edge, same MLP. Accum order per
//   feat unchanged -> absmax bit-identical. Unroll 4 (VGPR<=64 @ 8 w/EU).
// ---------------------------------------------------------------------------

static inline size_t ws_align(size_t x) { return (x + 255) & ~(size_t)255; }

typedef float __f2 __attribute__((ext_vector_type(2)));
typedef float __f4 __attribute__((ext_vector_type(4)));
typedef __attribute__((ext_vector_type(8))) short short8v;
typedef __attribute__((ext_vector_type(4))) float f32x4;

__device__ __forceinline__ int eidx(const void* p, size_t i, int is64) {
  return is64 ? (int)((const long long*)p)[i] : ((const int*)p)[i];
}

__device__ __forceinline__ uint16_t f2bf(float f) {  // RNE float->bf16
  uint32_t u = __float_as_uint(f);
  u += 0x7fffu + ((u >> 16) & 1u);
  return (uint16_t)(u >> 16);
}
__device__ __forceinline__ float bf_lo(uint32_t h) { return __uint_as_float(h << 16); }
__device__ __forceinline__ float bf_hi(uint32_t h) { return __uint_as_float(h & 0xffff0000u); }

// Detect int64 vs int32 edge_index (little-endian: int64 high words are 0).
__global__ void detect_k(const int* ei, int* flag) {
  if (threadIdx.x == 0 && blockIdx.x == 0) {
    int allz = 1;
    for (int i = 1; i < 128; i += 2)
      if (ei[i] != 0) { allz = 0; break; }
    *flag = allz;
  }
}

// --- passA: bucket histogram via per-block LDS counters --------------------
__global__ __launch_bounds__(256) void passA_k(const void* ei, const int* __restrict__ flag,
                                               int* __restrict__ bucket_cnt, int E, int NB) {
  __shared__ int cnt[256];
  int t = threadIdx.x;
  cnt[t] = 0;
  __syncthreads();
  int is64 = *flag;
  for (int e = blockIdx.x * 256 + t; e < E; e += gridDim.x * 256) {
    int c = eidx(ei, (size_t)E + e, is64);
    atomicAdd(&cnt[c >> 9], 1);
  }
  __syncthreads();
  if (t < NB && cnt[t]) atomicAdd(&bucket_cnt[t], cnt[t]);
}

// --- bscan: exclusive scan of bucket_cnt -> bucket_offs; init gcursor ------
__global__ __launch_bounds__(256) void bscan_k(const int* __restrict__ bucket_cnt,
                                               int* __restrict__ bucket_offs,
                                               int* __restrict__ gcursor, int NB) {
  __shared__ int sh[256];
  int t = threadIdx.x;
  int v = (t < NB) ? bucket_cnt[t] : 0;
  sh[t] = v;
  __syncthreads();
  for (int off = 1; off < 256; off <<= 1) {
    int x = (t >= off) ? sh[t - off] : 0;
    __syncthreads();
    sh[t] += x;
    __syncthreads();
  }
  if (t < NB) {
    int excl = sh[t] - v;
    bucket_offs[t] = excl;
    gcursor[t] = excl;
  }
  if (t == NB - 1) bucket_offs[NB] = sh[t];
}

// --- passB: partition edges into bucket-contiguous epk_binned --------------
__global__ __launch_bounds__(256) void passB_k(const void* ei, const int* __restrict__ flag,
                                               int* __restrict__ gcursor,
                                               int2* __restrict__ epk_binned, int E, int NB) {
  __shared__ int2 sorted[4096];                       // 32 KB
  __shared__ int cnt[256], bbase[256], gb[256], cur[256];
  const int t = threadIdx.x;
  const int base = blockIdx.x * 4096;
  const int CH = min(4096, E - base);
  const int is64 = *flag;

  cnt[t] = 0;
  __syncthreads();
  for (int i = t; i < CH; i += 256) {
    int c = eidx(ei, (size_t)E + base + i, is64);
    atomicAdd(&cnt[c >> 9], 1);
  }
  __syncthreads();
  {
    int v = cnt[t];
    __shared__ int sh[256];
    sh[t] = v;
    __syncthreads();
    for (int off = 1; off < 256; off <<= 1) {
      int x = (t >= off) ? sh[t - off] : 0;
      __syncthreads();
      sh[t] += x;
      __syncthreads();
    }
    bbase[t] = sh[t] - v;
    gb[t] = (t < NB && v) ? atomicAdd(&gcursor[t], v) : 0;
    cur[t] = 0;
  }
  __syncthreads();
  for (int i = t; i < CH; i += 256) {
    int r = eidx(ei, (size_t)base + i, is64);
    int c = eidx(ei, (size_t)E + base + i, is64);
    int b = c >> 9;
    int rank = atomicAdd(&cur[b], 1);
    sorted[bbase[b] + rank] = make_int2(r, c);
  }
  __syncthreads();
  for (int i = t; i < CH; i += 256) {
    int2 v = sorted[i];
    int b = v.y >> 9;
    epk_binned[gb[b] + (i - bbase[b])] = v;
  }
}

// --- passC0: per-bucket degree count -> deg[] and offs[] (coalesced) -------
__global__ __launch_bounds__(256) void passC0_k(const int2* __restrict__ epk_binned,
                                                const int* __restrict__ bucket_offs,
                                                int* __restrict__ deg, int* __restrict__ offs,
                                                int n, int NB) {
  __shared__ int dcnt[512];
  __shared__ int s[256];
  const int t = threadIdx.x;
  const int b = blockIdx.x;
  dcnt[t] = 0; dcnt[t + 256] = 0;
  __syncthreads();
  const int lo = bucket_offs[b], hi = bucket_offs[b + 1];
  for (int i = lo + t; i < hi; i += 256)
    atomicAdd(&dcnt[epk_binned[i].y & 511], 1);
  __syncthreads();
  int d0 = dcnt[2 * t], d1 = dcnt[2 * t + 1];
  int pv = d0 + d1;
  s[t] = pv;
  __syncthreads();
  for (int off = 1; off < 256; off <<= 1) {
    int x = (t >= off) ? s[t - off] : 0;
    __syncthreads();
    s[t] += x;
    __syncthreads();
  }
  int pex = s[t] - pv;
  const int node0 = b << 9;
  int g0 = node0 + 2 * t, g1 = node0 + 2 * t + 1;
  if (g0 < n) { deg[g0] = d0; offs[g0] = lo + pex; }
  if (g1 < n) { deg[g1] = d1; offs[g1] = lo + pex + d0; }
  if (b == NB - 1 && t == 0) offs[n] = hi;
}

__global__ void dinv_k(const int* __restrict__ deg, float* __restrict__ dinv, int n) {
  int i = blockIdx.x * blockDim.x + threadIdx.x;
  if (i < n) dinv[i] = rsqrtf((float)deg[i] + 1.0f);  // +1 = self loop
}

// --- passC: final placement by exact dest; entry = plain src ---------------
__global__ __launch_bounds__(256) void passC_k(const int2* __restrict__ epk_binned,
                                               const int* __restrict__ bucket_offs,
                                               const int* __restrict__ offs,
                                               uint32_t* __restrict__ epk) {
  __shared__ int cur[512];
  const int t = threadIdx.x;
  const int b = blockIdx.x;
  cur[t] = 0; cur[t + 256] = 0;
  __syncthreads();
  const int lo = bucket_offs[b], hi = bucket_offs[b + 1];
  for (int i = lo + t; i < hi; i += 256) {
    int2 v = epk_binned[i];
    int pos = offs[v.y] + atomicAdd(&cur[v.y & 511], 1);
    epk[pos] = (uint32_t)v.x;
  }
}

// --- wprep: split W fp32 -> bf16 hi/lo MFMA fragments in global ------------
template <int COLS>
__global__ void wprep_k(const float* __restrict__ W, uint16_t* __restrict__ Wf) {
  constexpr int CT = COLS / 16;
  const int f = blockIdx.x;  // [0, 4*CT)
  const int kc = f / CT, ct = f % CT;
  const int l = threadIdx.x;  // 0..63
#pragma unroll
  for (int j = 0; j < 8; ++j) {
    int k = kc * 32 + (l >> 4) * 8 + j;
    int col = ct * 16 + (l & 15);
    float wv = W[(size_t)k * COLS + col];
    uint16_t hi = f2bf(wv);
    float res = wv - __uint_as_float((uint32_t)hi << 16);
    Wf[(size_t)f * 1024 + l * 8 + j] = hi;
    Wf[(size_t)f * 1024 + 512 + l * 8 + j] = f2bf(res);
  }
}

// --- MFMA GEMM: Hs (32-feat-sliced bf16) = dinv[row] * (X @ W) -------------
// X read dense (layer 0) or 32-feat-sliced fp32 (layers 1/2).
template <int COLS, bool SLICED_IN>
__global__ __launch_bounds__(256) void gemm_k(const float* __restrict__ X,
                                              const uint16_t* __restrict__ Wf,
                                              const float* __restrict__ dinv,
                                              uint16_t* __restrict__ H, int N) {
  constexpr int CT = COLS / 16;
  __shared__ uint32_t Xp[128 * 32];  // 16 KB

  const int tid = threadIdx.x;
  const int l = tid & 63, w = tid >> 6;
  const int rowbase = blockIdx.x * 128;
  const float4* X4 = (const float4*)X;

  f32x4 acc[2][CT];
#pragma unroll
  for (int rt = 0; rt < 2; ++rt)
#pragma unroll
    for (int ct = 0; ct < CT; ++ct) acc[rt][ct] = (f32x4)0.f;

  for (int kc = 0; kc < 4; ++kc) {
    __syncthreads();
    // stage X chunk: 128 rows x 32 k, packed bf16 hi/lo, swizzled
#pragma unroll
    for (int t = 0; t < 4; ++t) {
      int i = tid + t * 256;  // 0..1023
      int r = i >> 3, q = i & 7;
      int gr = rowbase + r;
      if (gr >= N) gr = N - 1;
      float4 xv;
      if (SLICED_IN) {
        int s = kc, qq = q;
        xv = X4[((size_t)s * N + gr) * 8 + qq];
      } else {
        xv = X4[(size_t)gr * 32 + kc * 8 + q];
      }
      float xs[4] = {xv.x, xv.y, xv.z, xv.w};
      uint32_t p[4];
#pragma unroll
      for (int e = 0; e < 4; ++e) {
        uint16_t hi = f2bf(xs[e]);
        float res = xs[e] - __uint_as_float((uint32_t)hi << 16);
        p[e] = ((uint32_t)hi << 16) | (uint32_t)f2bf(res);
      }
      int blk = q ^ (r & 7);
      *(uint4*)&Xp[r * 32 + blk * 4] = make_uint4(p[0], p[1], p[2], p[3]);
    }
    __syncthreads();

    // A fragments (2 row-tiles), unpack hi/lo via v_perm
    short8v ah[2], al[2];
#pragma unroll
    for (int rt = 0; rt < 2; ++rt) {
      int r = w * 32 + rt * 16 + (l & 15);
      int c = (r & 7) << 2;
      int b0 = ((l >> 4) * 8) ^ c;
      int b1 = ((l >> 4) * 8 + 4) ^ c;
      uint32_t ua[8];
      *(uint4*)&ua[0] = *(const uint4*)&Xp[r * 32 + b0];
      *(uint4*)&ua[4] = *(const uint4*)&Xp[r * 32 + b1];
      union { uint32_t d[4]; short8v v; } ch, cl;
#pragma unroll
      for (int p2 = 0; p2 < 4; ++p2) {
        ch.d[p2] = __builtin_amdgcn_perm(ua[2 * p2 + 1], ua[2 * p2], 0x07060302u);
        cl.d[p2] = __builtin_amdgcn_perm(ua[2 * p2 + 1], ua[2 * p2], 0x05040100u);
      }
      ah[rt] = ch.v;
      al[rt] = cl.v;
    }

    // B fragments from global (L2), 3-term mfma
#pragma unroll
    for (int ct = 0; ct < CT; ++ct) {
      size_t fo = (size_t)(kc * CT + ct) * 1024;
      short8v bh = *(const short8v*)(Wf + fo + l * 8);
      short8v bl = *(const short8v*)(Wf + fo + 512 + l * 8);
#pragma unroll
      for (int rt = 0; rt < 2; ++rt) {
        acc[rt][ct] = __builtin_amdgcn_mfma_f32_16x16x32_bf16(ah[rt], bh, acc[rt][ct], 0, 0, 0);
        acc[rt][ct] = __builtin_amdgcn_mfma_f32_16x16x32_bf16(al[rt], bh, acc[rt][ct], 0, 0, 0);
        acc[rt][ct] = __builtin_amdgcn_mfma_f32_16x16x32_bf16(ah[rt], bl, acc[rt][ct], 0, 0, 0);
      }
    }
  }

  // Epilogue: D col=lane&15, row=(lane>>4)*4+reg. Pair even/odd cols via
  // shfl_xor -> uint32 words, sliced-bf16 H layout (same as agg expects).
  uint32_t* HW = (uint32_t*)H;
  const int lq = l >> 4, lc = l & 15;
#pragma unroll
  for (int rt = 0; rt < 2; ++rt) {
#pragma unroll
    for (int q = 0; q < 4; ++q) {
      int row = rowbase + w * 32 + rt * 16 + lq * 4 + q;
      bool ok = row < N;
      float dv = ok ? dinv[row] : 0.f;
#pragma unroll
      for (int ct = 0; ct < CT; ++ct) {
        float v = acc[rt][ct][q] * dv;
        int b = (int)f2bf(v);
        int other = __shfl_xor(b, 1);
        if (ok && !(l & 1)) {
          uint32_t word = (uint32_t)b | ((uint32_t)other << 16);
          HW[((size_t)(ct >> 1) * N + row) * 16 + (ct & 1) * 8 + (lc >> 1)] = word;
        }
      }
    }
  }
}

// --- Sliced aggregate, 128 feats: 4 slices x 32 feats, slice = blockIdx&3 --
// R12: 4-lane subgroups, lane w gathers uint4 = feats 8w..8w+7.
// 4 lanes x 16B = full 64B line per (dest,edge); wave covers 16 dests.
__global__ __launch_bounds__(256, 8) void agg128s_k(const uint32_t* __restrict__ HW,
                                                    const int* __restrict__ offs,
                                                    const uint32_t* __restrict__ epk,
                                                    const float* __restrict__ bias,
                                                    float* __restrict__ Aout,
                                                    int relu, int N) {
  const int s = blockIdx.x & 3;
  const int g = blockIdx.x >> 2;
  const int lane = threadIdx.x & 63;
  const int wid = threadIdx.x >> 6;
  const int d = lane >> 2, w = lane & 3;
  const int c = g * 64 + wid * 16 + d;
  if (c >= N) return;
  const uint32_t* Hs = HW + (size_t)s * N * 16;
  const int wq = 4 * w;
  int e0 = offs[c], e1 = offs[c + 1];
  float a0 = 0.f, a1 = 0.f, a2 = 0.f, a3 = 0.f;
  float a4 = 0.f, a5 = 0.f, a6 = 0.f, a7 = 0.f;
  int e = e0;
  for (; e + 4 <= e1; e += 4) {
    uint32_t p0 = epk[e], p1 = epk[e + 1], p2 = epk[e + 2], p3 = epk[e + 3];
    uint4 h0 = *(const uint4*)&Hs[(size_t)p0 * 16 + wq];
    uint4 h1 = *(const uint4*)&Hs[(size_t)p1 * 16 + wq];
    uint4 h2 = *(const uint4*)&Hs[(size_t)p2 * 16 + wq];
    uint4 h3 = *(const uint4*)&Hs[(size_t)p3 * 16 + wq];
    a0 += bf_lo(h0.x); a1 += bf_hi(h0.x); a2 += bf_lo(h0.y); a3 += bf_hi(h0.y);
    a4 += bf_lo(h0.z); a5 += bf_hi(h0.z); a6 += bf_lo(h0.w); a7 += bf_hi(h0.w);
    a0 += bf_lo(h1.x); a1 += bf_hi(h1.x); a2 += bf_lo(h1.y); a3 += bf_hi(h1.y);
    a4 += bf_lo(h1.z); a5 += bf_hi(h1.z); a6 += bf_lo(h1.w); a7 += bf_hi(h1.w);
    a0 += bf_lo(h2.x); a1 += bf_hi(h2.x); a2 += bf_lo(h2.y); a3 += bf_hi(h2.y);
    a4 += bf_lo(h2.z); a5 += bf_hi(h2.z); a6 += bf_lo(h2.w); a7 += bf_hi(h2.w);
    a0 += bf_lo(h3.x); a1 += bf_hi(h3.x); a2 += bf_lo(h3.y); a3 += bf_hi(h3.y);
    a4 += bf_lo(h3.z); a5 += bf_hi(h3.z); a6 += bf_lo(h3.w); a7 += bf_hi(h3.w);
  }
  for (; e < e1; ++e) {
    uint4 h = *(const uint4*)&Hs[(size_t)epk[e] * 16 + wq];
    a0 += bf_lo(h.x); a1 += bf_hi(h.x); a2 += bf_lo(h.y); a3 += bf_hi(h.y);
    a4 += bf_lo(h.z); a5 += bf_hi(h.z); a6 += bf_lo(h.w); a7 += bf_hi(h.w);
  }
  float dc = rsqrtf((float)(e1 - e0) + 1.f);
  uint4 hc = *(const uint4*)&Hs[(size_t)c * 16 + wq];
  const float* bs = bias + s * 32 + 8 * w;
  float r0 = fmaf(dc, a0 + bf_lo(hc.x), bs[0]);
  float r1 = fmaf(dc, a1 + bf_hi(hc.x), bs[1]);
  float r2 = fmaf(dc, a2 + bf_lo(hc.y), bs[2]);
  float r3 = fmaf(dc, a3 + bf_hi(hc.y), bs[3]);
  float r4 = fmaf(dc, a4 + bf_lo(hc.z), bs[4]);
  float r5 = fmaf(dc, a5 + bf_hi(hc.z), bs[5]);
  float r6 = fmaf(dc, a6 + bf_lo(hc.w), bs[6]);
  float r7 = fmaf(dc, a7 + bf_hi(hc.w), bs[7]);
  if (relu) {
    r0 = fmaxf(r0, 0.f); r1 = fmaxf(r1, 0.f); r2 = fmaxf(r2, 0.f); r3 = fmaxf(r3, 0.f);
    r4 = fmaxf(r4, 0.f); r5 = fmaxf(r5, 0.f); r6 = fmaxf(r6, 0.f); r7 = fmaxf(r7, 0.f);
  }
  float* OP = Aout + ((size_t)s * N + c) * 32 + 8 * w;
  __f4 lo4; lo4.x = r0; lo4.y = r1; lo4.z = r2; lo4.w = r3;
  __f4 hi4; hi4.x = r4; hi4.y = r5; hi4.z = r6; hi4.w = r7;
  __builtin_nontemporal_store(lo4, (__f4*)OP);
  __builtin_nontemporal_store(hi4, (__f4*)(OP + 4));
}

// --- Sliced aggregate, 64 feats: 2 slices x 32 on XCD quads; dense out -----
// R12: 4-lane x uint4 subgroups (16 dests/wave).
__global__ __launch_bounds__(256, 8) void agg64s_k(const uint32_t* __restrict__ HW,
                                                   const int* __restrict__ offs,
                                                   const uint32_t* __restrict__ epk,
                                                   const float* __restrict__ bias,
                                                   float* __restrict__ out, int N) {
  const int r = blockIdx.x & 7;
  const int s = r >> 2;          // slice 0..1 (32 feats each)
  const int quar = r & 3;
  const int ng = (N + 63) >> 6;
  const int nq = (ng + 3) >> 2;
  const int g = quar * nq + (blockIdx.x >> 3);
  if (g >= ng) return;
  const int lane = threadIdx.x & 63;
  const int wid = threadIdx.x >> 6;
  const int d = lane >> 2, w = lane & 3;
  const int c = g * 64 + wid * 16 + d;
  if (c >= N) return;
  const uint32_t* Hs = HW + (size_t)s * N * 16;
  const int wq = 4 * w;
  int e0 = offs[c], e1 = offs[c + 1];
  float a0 = 0.f, a1 = 0.f, a2 = 0.f, a3 = 0.f;
  float a4 = 0.f, a5 = 0.f, a6 = 0.f, a7 = 0.f;
  int e = e0;
  for (; e + 4 <= e1; e += 4) {
    uint32_t p0 = epk[e], p1 = epk[e + 1], p2 = epk[e + 2], p3 = epk[e + 3];
    uint4 h0 = *(const uint4*)&Hs[(size_t)p0 * 16 + wq];
    uint4 h1 = *(const uint4*)&Hs[(size_t)p1 * 16 + wq];
    uint4 h2 = *(const uint4*)&Hs[(size_t)p2 * 16 + wq];
    uint4 h3 = *(const uint4*)&Hs[(size_t)p3 * 16 + wq];
    a0 += bf_lo(h0.x); a1 += bf_hi(h0.x); a2 += bf_lo(h0.y); a3 += bf_hi(h0.y);
    a4 += bf_lo(h0.z); a5 += bf_hi(h0.z); a6 += bf_lo(h0.w); a7 += bf_hi(h0.w);
    a0 += bf_lo(h1.x); a1 += bf_hi(h1.x); a2 += bf_lo(h1.y); a3 += bf_hi(h1.y);
    a4 += bf_lo(h1.z); a5 += bf_hi(h1.z); a6 += bf_lo(h1.w); a7 += bf_hi(h1.w);
    a0 += bf_lo(h2.x); a1 += bf_hi(h2.x); a2 += bf_lo(h2.y); a3 += bf_hi(h2.y);
    a4 += bf_lo(h2.z); a5 += bf_hi(h2.z); a6 += bf_lo(h2.w); a7 += bf_hi(h2.w);
    a0 += bf_lo(h3.x); a1 += bf_hi(h3.x); a2 += bf_lo(h3.y); a3 += bf_hi(h3.y);
    a4 += bf_lo(h3.z); a5 += bf_hi(h3.z); a6 += bf_lo(h3.w); a7 += bf_hi(h3.w);
  }
  for (; e < e1; ++e) {
    uint4 h = *(const uint4*)&Hs[(size_t)epk[e] * 16 + wq];
    a0 += bf_lo(h.x); a1 += bf_hi(h.x); a2 += bf_lo(h.y); a3 += bf_hi(h.y);
    a4 += bf_lo(h.z); a5 += bf_hi(h.z); a6 += bf_lo(h.w); a7 += bf_hi(h.w);
  }
  float dc = rsqrtf((float)(e1 - e0) + 1.f);
  uint4 hc = *(const uint4*)&Hs[(size_t)c * 16 + wq];
  const float* bs = bias + s * 32 + 8 * w;
  float r0 = fmaf(dc, a0 + bf_lo(hc.x), bs[0]);
  float r1 = fmaf(dc, a1 + bf_hi(hc.x), bs[1]);
  float r2 = fmaf(dc, a2 + bf_lo(hc.y), bs[2]);
  float r3 = fmaf(dc, a3 + bf_hi(hc.y), bs[3]);
  float r4 = fmaf(dc, a4 + bf_lo(hc.z), bs[4]);
  float r5 = fmaf(dc, a5 + bf_hi(hc.z), bs[5]);
  float r6 = fmaf(dc, a6 + bf_lo(hc.w), bs[6]);
  float r7 = fmaf(dc, a7 + bf_hi(hc.w), bs[7]);
  float* OP = out + (size_t)c * 64 + s * 32 + 8 * w;
  __f4 lo4; lo4.x = r0; lo4.y = r1; lo4.z = r2; lo4.w = r3;
  __f4 hi4; hi4.x = r4; hi4.y = r5; hi4.z = r6; hi4.w = r7;
  __builtin_nontemporal_store(lo4, (__f4*)OP);
  __builtin_nontemporal_store(hi4, (__f4*)(OP + 4));
}

extern "C" void kernel_launch(void* const* d_in, const int* in_sizes, int n_in,
                              void* d_out, int out_size, void* d_ws, size_t ws_size,
                              hipStream_t stream) {
  const float* x  = (const float*)d_in[0];
  const void*  ei = d_in[1];
  const float* W0 = (const float*)d_in[2];
  const float* b0 = (const float*)d_in[3];
  const float* W1 = (const float*)d_in[4];
  const float* b1 = (const float*)d_in[5];
  const float* W2 = (const float*)d_in[6];
  const float* b2 = (const float*)d_in[7];
  float* out = (float*)d_out;

  const int n = in_sizes[0] / 128;   // 100000
  const int E = in_sizes[1] / 2;     // 1600000
  const int NB = (n + 511) >> 9;     // buckets of 512 dests (NB <= 256)

  char* ws = (char*)d_ws;
  size_t off = 0;
  auto alloc = [&](size_t bytes) { char* p = ws + off; off = ws_align(off + bytes); return p; };
  int*      bucket_cnt  = (int*)alloc(256 * 4);
  int*      bucket_offs = (int*)alloc(257 * 4);
  int*      gcursor     = (int*)alloc(256 * 4);
  int*      deg         = (int*)alloc((size_t)n * 4);
  int*      offs        = (int*)alloc((size_t)(n + 1) * 4);
  float*    dinv        = (float*)alloc((size_t)n * 4);
  int*      flag        = (int*)alloc(4);
  uint16_t* wf0         = (uint16_t*)alloc(64 * 1024);
  uint16_t* wf1         = (uint16_t*)alloc(64 * 1024);
  uint16_t* wf2         = (uint16_t*)alloc(32 * 1024);
  int2*     epk_binned  = (int2*)alloc((size_t)E * 8);
  uint32_t* epk         = (uint32_t*)alloc((size_t)E * 4);
  uint16_t* hbuf        = (uint16_t*)alloc((size_t)n * 128 * 2);  // sliced bf16 H'
  float*    abuf        = (float*)alloc((size_t)n * 128 * 4);     // sliced fp32 acts
  (void)ws_size;

  hipMemsetAsync(bucket_cnt, 0, 256 * 4, stream);

  // W split/fragment prep (independent of graph passes)
  wprep_k<128><<<32, 64, 0, stream>>>(W0, wf0);
  wprep_k<128><<<32, 64, 0, stream>>>(W1, wf1);
  wprep_k<64><<<16, 64, 0, stream>>>(W2, wf2);

  detect_k<<<1, 64, 0, stream>>>((const int*)ei, flag);
  passA_k<<<512, 256, 0, stream>>>(ei, flag, bucket_cnt, E, NB);
  bscan_k<<<1, 256, 0, stream>>>(bucket_cnt, bucket_offs, gcursor, NB);
  passB_k<<<(E + 4095) / 4096, 256, 0, stream>>>(ei, flag, gcursor, epk_binned, E, NB);
  passC0_k<<<NB, 256, 0, stream>>>(epk_binned, bucket_offs, deg, offs, n, NB);
  dinv_k<<<(n + 255) / 256, 256, 0, stream>>>(deg, dinv, n);
  passC_k<<<NB, 256, 0, stream>>>(epk_binned, bucket_offs, offs, epk);

  const int gemm_blocks = (n + 127) / 128;
  const int agg128_blocks = 4 * ((n + 63) / 64);
  const int ng = (n + 63) >> 6, nq = (ng + 3) >> 2;
  const int agg64_blocks = 8 * nq;

  // Layer 0 (dense x input)
  gemm_k<128, false><<<gemm_blocks, 256, 0, stream>>>(x, wf0, dinv, hbuf, n);
  agg128s_k<<<agg128_blocks, 256, 0, stream>>>((const uint32_t*)hbuf, offs, epk, b0, abuf, 1, n);
  // Layer 1 (sliced activations)
  gemm_k<128, true><<<gemm_blocks, 256, 0, stream>>>(abuf, wf1, dinv, hbuf, n);
  agg128s_k<<<agg128_blocks, 256, 0, stream>>>((const uint32_t*)hbuf, offs, epk, b1, abuf, 1, n);
  // Layer 2 (no relu) -> d_out dense fp32
  gemm_k<64, true><<<gemm_blocks, 256, 0, stream>>>(abuf, wf2, dinv, hbuf, n);
  agg64s_k<<<agg64_blocks, 256, 0, stream>>>((const uint32_t*)hbuf, offs, epk, b2, out, n);
}